// Round 7
// baseline (165.639 us; speedup 1.0000x reference)
//
#include <hip/hip_runtime.h>
#include <math.h>

// NoisyTopkRouter, all-f32.
// x[ntok,384] @ {w_route,w_noise}[8,384]^T -> 16 logits/token,
// noisy = logit + noise*softplus(noise_logit), top-2 of 8, sparse softmax.
// Output: [ntok*8 probs f32 | ntok*2 indices-as-f32].
//
// R7: expert-split + 4 tokens/thread. Total LDS instrs scale as 1/(tokens per
// thread); T=4 with all 16 experts spilled (R4). Splitting experts across lane
// pairs (even=route 8, odd=noise 8) keeps acc[4][8]=32 regs -> ~100 VGPR, no
// spill. Paired lanes issue identical x addresses (coalescer dedups). VALU is
// at the exact useful-FMA floor; LDS instrs halved vs R6; 2048 blocks.

constexpr int D = 384;

__device__ __forceinline__ float dpp_xor1(float v) {   // lane ^ 1, quad_perm [1,0,3,2]
    return __int_as_float(__builtin_amdgcn_update_dpp(
        0, __float_as_int(v), 0xB1, 0xF, 0xF, true));
}
__device__ __forceinline__ float dpp_xor2(float v) {   // lane ^ 2, quad_perm [2,3,0,1]
    return __int_as_float(__builtin_amdgcn_update_dpp(
        0, __float_as_int(v), 0x4E, 0xF, 0xF, true));
}
__device__ __forceinline__ float swz_xor4(float v) {   // ds_swizzle xor 4
    return __int_as_float(__builtin_amdgcn_ds_swizzle(__float_as_int(v), 0x101F));
}
__device__ __forceinline__ float swz_xor8(float v) {   // ds_swizzle xor 8
    return __int_as_float(__builtin_amdgcn_ds_swizzle(__float_as_int(v), 0x201F));
}
__device__ __forceinline__ float swz_xor16(float v) {  // ds_swizzle xor 16
    return __int_as_float(__builtin_amdgcn_ds_swizzle(__float_as_int(v), 0x401F));
}

__global__ __launch_bounds__(256, 4) void noisy_topk_router_f32(
    const float* __restrict__ x,        // [ntok,384]
    const float* __restrict__ noise,    // [ntok,8]
    const float* __restrict__ w_route,  // [8,384]
    const float* __restrict__ b_route,  // [8]
    const float* __restrict__ w_noise,  // [8,384]
    const float* __restrict__ b_noise,  // [8]
    float* __restrict__ out,            // [ntok*8 | ntok*2]
    int ntok)
{
    __shared__ float w_lds[16 * D];   // rows: e=0..7 route, e=8..15 noise
    __shared__ float bias[16];

    const int tid = threadIdx.x;

    // stage weights: 2 x 3072 floats = 2 x 768 float4; 256 threads x 3 each
#pragma unroll
    for (int r = 0; r < 3; ++r) {
        int i = (tid + 256 * r) * 4;                       // < 3072
        *(float4*)(w_lds + i)        = *(const float4*)(w_route + i);
        *(float4*)(w_lds + 3072 + i) = *(const float4*)(w_noise + i);
    }
    if (tid < 8)       bias[tid] = b_route[tid];
    else if (tid < 16) bias[tid] = b_noise[tid - 8];
    __syncthreads();

    const int wave = tid >> 6;
    const int lane = tid & 63;
    const int p    = lane & 1;          // 0: route experts, 1: noise experts
    const int c    = (lane >> 1) & 15;  // d-slice 0..15 (24 d each)
    const int g    = lane >> 5;         // token-group 0..1
    // thread owns 4 tokens; wave covers 8; block covers 32
    const int tok0 = blockIdx.x * 32 + wave * 8 + g * 4;

    float acc[4][8];
#pragma unroll
    for (int t = 0; t < 4; ++t)
#pragma unroll
        for (int e = 0; e < 8; ++e) acc[t][e] = 0.f;

    // chunk j (0..5): lane c covers d = j*64 + c*4 .. +4 (16 slices = 256B contiguous)
    const float* xr = x + (size_t)tok0 * D + c * 4;
    const float* wb = w_lds + (p * 8) * D + c * 4;

    float4 xa[4], xn[4];
#pragma unroll
    for (int t = 0; t < 4; ++t) xa[t] = *(const float4*)(xr + t * D);

#pragma unroll
    for (int j = 0; j < 6; ++j) {
        const int jn = (j < 5) ? (j + 1) * 64 : 0;   // last prefetch: dummy re-read
#pragma unroll
        for (int t = 0; t < 4; ++t) xn[t] = *(const float4*)(xr + t * D + jn);

        const float* wj = wb + j * 64;
#pragma unroll
        for (int e = 0; e < 8; ++e) {
            float4 wv = *(const float4*)(wj + e * D);
            acc[0][e] += xa[0].x * wv.x + xa[0].y * wv.y + xa[0].z * wv.z + xa[0].w * wv.w;
            acc[1][e] += xa[1].x * wv.x + xa[1].y * wv.y + xa[1].z * wv.z + xa[1].w * wv.w;
            acc[2][e] += xa[2].x * wv.x + xa[2].y * wv.y + xa[2].z * wv.z + xa[2].w * wv.w;
            acc[3][e] += xa[3].x * wv.x + xa[3].y * wv.y + xa[3].z * wv.z + xa[3].w * wv.w;
        }
#pragma unroll
        for (int t = 0; t < 4; ++t) xa[t] = xn[t];
    }

    // Reduce over the 16 d-slices (lane bits 1..4), partitioned by token bits:
    // xor2 keeps token bit0 == c&1; xor4 keeps token bit1 == (c>>1)&1;
    // xor8/xor16 plain. Afterwards: token tok0 + (c&3), experts p*8+e.
    const bool b0 = (c & 1), b1 = (c >> 1) & 1;
    float a2[2][8];
#pragma unroll
    for (int u = 0; u < 2; ++u)
#pragma unroll
        for (int e = 0; e < 8; ++e) {
            float s = b0 ? acc[2 * u][e]     : acc[2 * u + 1][e];   // send
            float k = b0 ? acc[2 * u + 1][e] : acc[2 * u][e];       // keep
            a2[u][e] = k + dpp_xor2(s);
        }
    float a1[8];
#pragma unroll
    for (int e = 0; e < 8; ++e) {
        float s = b1 ? a2[0][e] : a2[1][e];
        float k = b1 ? a2[1][e] : a2[0][e];
        a1[e] = k + swz_xor4(s);
    }
#pragma unroll
    for (int e = 0; e < 8; ++e) a1[e] += swz_xor8(a1[e]);
#pragma unroll
    for (int e = 0; e < 8; ++e) a1[e] += swz_xor16(a1[e]);

    // pair exchange: even lane holds route sums, odd lane holds noise sums
    float oth[8];
#pragma unroll
    for (int e = 0; e < 8; ++e) oth[e] = dpp_xor1(a1[e]);

    if (p == 0 && c < 4) {
        const int token = tok0 + c;        // 8 active lanes/wave, 8 tokens/wave
        float4 n0 = *(const float4*)(noise + (size_t)token * 8);
        float4 n1 = *(const float4*)(noise + (size_t)token * 8 + 4);
        float nz[8] = {n0.x, n0.y, n0.z, n0.w, n1.x, n1.y, n1.z, n1.w};

        float noisy[8];
#pragma unroll
        for (int e = 0; e < 8; ++e) {
            float lg = a1[e]  + bias[e];        // route
            float nl = oth[e] + bias[8 + e];    // noise logits
            // stable softplus: max(z,0) + log1p(exp(-|z|))
            float sp = fmaxf(nl, 0.f) + log1pf(expf(-fabsf(nl)));
            noisy[e] = lg + nz[e] * sp;
        }

        // top-2, jax.lax.top_k tie-break: earliest index wins ties
        float v0 = noisy[0]; int i0 = 0;
#pragma unroll
        for (int e = 1; e < 8; ++e)
            if (noisy[e] > v0) { v0 = noisy[e]; i0 = e; }
        float v1 = -INFINITY; int i1 = 0;
#pragma unroll
        for (int e = 0; e < 8; ++e)
            if (e != i0 && noisy[e] > v1) { v1 = noisy[e]; i1 = e; }

        // 2-way softmax (other experts exactly 0)
        float ex  = expf(v1 - v0);       // v1 <= v0
        float inv = 1.f / (1.f + ex);
        float p0  = inv;
        float p1  = ex * inv;

        float pr[8];
#pragma unroll
        for (int e = 0; e < 8; ++e)
            pr[e] = (e == i0) ? p0 : ((e == i1) ? p1 : 0.f);

        float* orow = out + (size_t)token * 8;
        *(float4*)(orow)     = make_float4(pr[0], pr[1], pr[2], pr[3]);
        *(float4*)(orow + 4) = make_float4(pr[4], pr[5], pr[6], pr[7]);

        *(float2*)(out + (size_t)ntok * 8 + (size_t)token * 2) =
            make_float2((float)i0, (float)i1);
    }
}

extern "C" void kernel_launch(void* const* d_in, const int* in_sizes, int n_in,
                              void* d_out, int out_size, void* d_ws, size_t ws_size,
                              hipStream_t stream) {
    const float* x       = (const float*)d_in[0];
    const float* noise   = (const float*)d_in[1];
    const float* w_route = (const float*)d_in[2];
    const float* b_route = (const float*)d_in[3];
    const float* w_noise = (const float*)d_in[4];
    const float* b_noise = (const float*)d_in[5];
    float* out = (float*)d_out;

    const int ntok   = in_sizes[0] / D;   // 65536
    const int blocks = ntok / 32;         // 32 tokens per 256-thread block

    hipLaunchKernelGGL(noisy_topk_router_f32, dim3(blocks), dim3(256), 0, stream,
                       x, noise, w_route, b_route, w_noise, b_noise, out, ntok);
}